// Round 10
// baseline (586.423 us; speedup 1.0000x reference)
//
#include <hip/hip_runtime.h>
#include <cstdint>
#include <cstddef>

// ---------------------------------------------------------------------------
// DynamicMemoryCell on MI355X (gfx950) — round 13
//
// Math: softmax over 1 key == 1 -> attn == v; q/k/pm dead.
// Linear chain pi->v->ctx->gi collapsed: Wcomb = Wih@Wop@Wv@Wip (per call).
// GRU algebra: r,z need only SUMS gi+gh -> one two-phase-K GEMM; combine
// fused into gh_n GEMM epilogue.
//
// Round-13 vs round-12 (435us): rounds 6/7/9 accounting shows the
// measured-vs-kernel-sum residual is FIXED (~180us) regardless of launch
// count -> it's harness/reset overhead, not per-launch gap. Only kernel
// work reductions pay. This round: reassociate the weight composition
//   Wcomb = (Wih@Wop) @ (Wv@Wip)
// so the two inner products are INDEPENDENT and share a launch with fg:
//   L1 prep_k  : cat + 5 casts + Wip^T + Wop^T + ones + gemv1
//   L2 comb1_k : T1T=(Wv@Wip)^T + P=Wih@Wop + gemv2 + FG
//   L3 comb2_k : Wcomb = P@T1T + gemv3
//   L4 big_k   : Grz (two-phase K) + gi_n
//   L5 g3_k    : gh_n + fused GRU combine -> UPD
//   L6 og_k    : out = upd * sig(upd@Wog^T+bog)
// 7 -> 6 launches; standalone gemm64 launch eliminated (P's extra 6 GFLOP
// hides under fg). GEMM cores byte-identical to round-12 (verified).
// ---------------------------------------------------------------------------

typedef __bf16 bf16;
typedef bf16 bf16x4 __attribute__((ext_vector_type(4)));
typedef bf16 bf16x8 __attribute__((ext_vector_type(8)));
typedef float f32x4 __attribute__((ext_vector_type(4)));

#define B_ROWS 8192

__device__ __forceinline__ float sigmoid_f(float x) {
    return 1.0f / (1.0f + __expf(-x));
}
__device__ __forceinline__ float tanh_f(float x) {
    return 1.0f - 2.0f / (__expf(2.0f * x) + 1.0f);
}

// ---------------------------------------------------------------------------
// 256x128 triple-buffered GEMM core (verified r10-r12). 4 waves (2Mx2N),
// wave tile 128x64, acc[8][4]. LDS 72 KiB (3-buf A/B); reused as C-stage.
// Counted vmcnt(6): one 6-load stage stays in flight across each barrier.
// Two K-phases: tiles [0,nt1) from A1/W1, [nt1,nt1+nt2) from A2/W2.
// EPI 0: out_bf = bf16(acc + bias1 [+ bias2])
// EPI 1: out_bf = bf16(aux_f32 * sigmoid(val))            (forget gate)
// EPI 2: out_f32 = float(aux_bf) * sigmoid(val)           (output gate)
// EPI 4: GRU combine: val = gh_n; r,z from GRZ, gi_n from GNI, mem from GAT
// ---------------------------------------------------------------------------
template <int EPI>
__device__ __forceinline__ void g256_core(
    bf16* lds,
    const bf16* A1, int lda1, const bf16* W1, int ldw1, int nt1,
    const bf16* A2, int lda2, const bf16* W2, int ldw2, int nt2,
    const float* bias1, const float* bias2,
    int N, int brow, int bcol,
    bf16* out_bf, float* out_f32,
    const float* aux_f32, const bf16* aux_bf,
    const bf16* grz, const bf16* gni, const bf16* gat)
{
    bf16* sA = lds;                       // 3 x 256 x 32
    bf16* sB = lds + 3 * 256 * 32;        // 3 x 128 x 32

    const int tid  = threadIdx.x;
    const int lane = tid & 63;
    const int wave = tid >> 6;
    const int wm   = wave >> 1;          // M half (128 rows)
    const int wn   = wave & 1;           // N half (64 cols)
    const int lrow = lane & 15;
    const int lq   = lane >> 4;

    f32x4 acc[8][4];
#pragma unroll
    for (int i = 0; i < 8; ++i)
#pragma unroll
        for (int j = 0; j < 4; ++j) {
            f32x4 z = {0.0f, 0.0f, 0.0f, 0.0f};
            acc[i][j] = z;
        }

    // stage K-tile kt: A 4 insts (256 rows), B 2 insts (128 rows). LDS dest
    // linear (rule #21); swizzle via permuted GLOBAL source col.
    auto stage = [&](bf16* dA, bf16* dB, int kt) {
        const bf16* Ab; int lda; const bf16* Wb; int ldw; int k0;
        if (kt < nt1) { Ab = A1; lda = lda1; Wb = W1; ldw = ldw1; k0 = kt << 5; }
        else          { Ab = A2; lda = lda2; Wb = W2; ldw = ldw2; k0 = (kt - nt1) << 5; }
#pragma unroll
        for (int i = 0; i < 4; ++i) {
            const int s   = tid + i * 256;
            const int row = s >> 2;
            const int col = (((s & 3) ^ ((s >> 3) & 3)) << 3);
            const bf16* gp = Ab + (size_t)(brow + row) * lda + (k0 + col);
            __builtin_amdgcn_global_load_lds(
                (const __attribute__((address_space(1))) void*)gp,
                (__attribute__((address_space(3))) void*)(&dA[s * 8]),
                16, 0, 0);
        }
#pragma unroll
        for (int i = 0; i < 2; ++i) {
            const int s   = tid + i * 256;
            const int row = s >> 2;
            const int col = (((s & 3) ^ ((s >> 3) & 3)) << 3);
            const bf16* gp = Wb + (size_t)(bcol + row) * ldw + (k0 + col);
            __builtin_amdgcn_global_load_lds(
                (const __attribute__((address_space(1))) void*)gp,
                (__attribute__((address_space(3))) void*)(&dB[s * 8]),
                16, 0, 0);
        }
    };

    const int NT = nt1 + nt2;

    bf16* a0 = sA;           bf16* b0 = sB;
    bf16* a1 = sA + 8192;    bf16* b1 = sB + 4096;
    bf16* a2 = sA + 16384;   bf16* b2 = sB + 8192;

    stage(a0, b0, 0);
    stage(a1, b1, 1);
    asm volatile("s_waitcnt vmcnt(6)" ::: "memory");  // tile 0 landed
    __builtin_amdgcn_s_barrier();
    __builtin_amdgcn_sched_barrier(0);

    for (int kt = 0; kt < NT; ++kt) {
        bf16x8 av[8], bv[4];
#pragma unroll
        for (int i = 0; i < 8; ++i) {
            const int r = wm * 128 + i * 16 + lrow;
            av[i] = *(const bf16x8*)&a0[r * 32 + ((lq ^ ((r >> 1) & 3)) << 3)];
        }
#pragma unroll
        for (int j = 0; j < 4; ++j) {
            const int r = wn * 64 + j * 16 + lrow;
            bv[j] = *(const bf16x8*)&b0[r * 32 + ((lq ^ ((r >> 1) & 3)) << 3)];
        }

        // tile kt+2 into the free buffer (tail re-stages: uniform FIFO)
        stage(a2, b2, kt + 2 < NT ? kt + 2 : NT - 1);

#pragma unroll
        for (int i = 0; i < 8; ++i)
#pragma unroll
            for (int j = 0; j < 4; ++j)
                acc[i][j] = __builtin_amdgcn_mfma_f32_16x16x32_bf16(
                    av[i], bv[j], acc[i][j], 0, 0, 0);

        __builtin_amdgcn_sched_barrier(0);
        asm volatile("s_waitcnt vmcnt(6)" ::: "memory"); // kt+1 landed
        __builtin_amdgcn_s_barrier();
        __builtin_amdgcn_sched_barrier(0);

        bf16* ta = a0; a0 = a1; a1 = a2; a2 = ta;
        bf16* tb = b0; b0 = b1; b1 = b2; b2 = tb;
    }

    // drain redundant tail stages; BLOCK barrier before LDS reuse (per-wave
    // vmcnt doesn't order other waves' in-flight global_load_lds writes)
    asm volatile("s_waitcnt vmcnt(0)" ::: "memory");
    __syncthreads();

    if constexpr (EPI == 0) {
        // ---- bf16 C-stage (stride 136: 2-way-max), coalesced b128 flush --
        bf16* cb = lds;
#pragma unroll
        for (int j = 0; j < 4; ++j) {
            const int col = wn * 64 + j * 16 + lrow;
            float bj = bias1[bcol + col];
            if (bias2) bj += bias2[bcol + col];
#pragma unroll
            for (int i = 0; i < 8; ++i) {
                const int rowb = wm * 128 + i * 16 + lq * 4;
#pragma unroll
                for (int r = 0; r < 4; ++r)
                    cb[(rowb + r) * 136 + col] = (bf16)(acc[i][j][r] + bj);
            }
        }
        __syncthreads();
#pragma unroll
        for (int p = 0; p < 16; ++p) {
            const int row = p * 16 + (tid >> 4);
            const int col = (tid & 15) * 8;
            bf16x8 v = *(const bf16x8*)&cb[row * 136 + col];
            *(bf16x8*)&out_bf[(size_t)(brow + row) * N + bcol + col] = v;
        }
    } else {
        // ---- f32 C-stage in two 128-row halves (exact activation input) --
        float* cf = (float*)lds;           // 128 x 132 f32 = 67.5 KiB
#pragma unroll
        for (int h = 0; h < 2; ++h) {
            if (wm == h) {
#pragma unroll
                for (int j = 0; j < 4; ++j) {
                    const int col = wn * 64 + j * 16 + lrow;
                    const float bj = bias1[bcol + col];
#pragma unroll
                    for (int i = 0; i < 8; ++i) {
                        const int rl = i * 16 + lq * 4;
#pragma unroll
                        for (int r = 0; r < 4; ++r)
                            cf[(rl + r) * 132 + col] = acc[i][j][r] + bj;
                    }
                }
            }
            __syncthreads();
#pragma unroll
            for (int p = 0; p < 16; ++p) {
                const int idx = p * 256 + tid;
                const int row = idx >> 5;
                const int ch  = idx & 31;
                f32x4 v = *(const f32x4*)&cf[row * 132 + ch * 4];
                const int grow = brow + h * 128 + row;
                const int gcol = bcol + ch * 4;
                const size_t gidx = (size_t)grow * N + gcol;
                if constexpr (EPI == 1) {
                    f32x4 a4 = *(const f32x4*)&aux_f32[gidx];
                    bf16x4 o;
#pragma unroll
                    for (int e = 0; e < 4; ++e)
                        o[e] = (bf16)(a4[e] * sigmoid_f(v[e]));
                    *(bf16x4*)&out_bf[gidx] = o;
                } else if constexpr (EPI == 2) {
                    bf16x4 ab = *(const bf16x4*)&aux_bf[gidx];
                    f32x4 o;
#pragma unroll
                    for (int e = 0; e < 4; ++e)
                        o[e] = (float)ab[e] * sigmoid_f(v[e]);
                    *(f32x4*)&out_f32[gidx] = o;
                } else {
                    // EPI == 4: GRU combine. v = gh_n (f32). N == 1024.
                    const bf16* pr = grz + (size_t)grow * 2048 + gcol;
                    bf16x4 rr = *(const bf16x4*)pr;          // r sums
                    bf16x4 zz = *(const bf16x4*)(pr + 1024); // z sums
                    bf16x4 g4 = *(const bf16x4*)&gni[gidx];  // gi_n
                    bf16x4 m4 = *(const bf16x4*)&gat[gidx];  // gated mem
                    bf16x4 o;
#pragma unroll
                    for (int e = 0; e < 4; ++e) {
                        const float r = sigmoid_f((float)rr[e]);
                        const float z = sigmoid_f((float)zz[e]);
                        const float n = tanh_f((float)g4[e] + r * v[e]);
                        o[e] = (bf16)((1.0f - z) * n + z * (float)m4[e]);
                    }
                    *(bf16x4*)&out_bf[gidx] = o;
                }
            }
            __syncthreads();
        }
    }
}

// ---------------------------------------------------------------------------
// Triple-buffered BM x 128 core (weight composition, verified).
// epi 0: out_bf = bf16(val);  epi 3: out_bf[gcol*tld + grow] (transposed)
// ---------------------------------------------------------------------------
template <int BM>
__device__ __forceinline__ void gemm_core_tb(
    bf16* sA, bf16* sB,
    const bf16* __restrict__ A, int lda,
    const bf16* __restrict__ W, int ldw,
    const float* __restrict__ bias,
    int N, int K, int brow, int bcol, int epi,
    bf16* __restrict__ out_bf, int tld)
{
    constexpr int AI = BM / 32;
    const int tid  = threadIdx.x;
    const int lane = tid & 63;
    const int wave = tid >> 6;
    const int wr   = (wave & 1) * (BM / 2);
    const int wc   = (wave >> 1) * 64;
    const int lrow = lane & 15;
    const int lq   = lane >> 4;

    f32x4 acc[AI][4];
#pragma unroll
    for (int i = 0; i < AI; ++i)
#pragma unroll
        for (int j = 0; j < 4; ++j) {
            f32x4 z = {0.0f, 0.0f, 0.0f, 0.0f};
            acc[i][j] = z;
        }

    auto stage = [&](bf16* dA, bf16* dB, int k0) {
#pragma unroll
        for (int i = 0; i < BM / 64; ++i) {
            const int s   = tid + i * 256;
            const int row = s >> 2;
            const int col = (((s & 3) ^ ((s >> 3) & 3)) << 3);
            const bf16* gp = A + (size_t)(brow + row) * lda + (k0 + col);
            __builtin_amdgcn_global_load_lds(
                (const __attribute__((address_space(1))) void*)gp,
                (__attribute__((address_space(3))) void*)(&dA[s * 8]),
                16, 0, 0);
        }
#pragma unroll
        for (int i = 0; i < 2; ++i) {
            const int s   = tid + i * 256;
            const int row = s >> 2;
            const int col = (((s & 3) ^ ((s >> 3) & 3)) << 3);
            const bf16* gp = W + (size_t)(bcol + row) * ldw + (k0 + col);
            __builtin_amdgcn_global_load_lds(
                (const __attribute__((address_space(1))) void*)gp,
                (__attribute__((address_space(3))) void*)(&dB[s * 8]),
                16, 0, 0);
        }
    };

#define WAIT_LPS()                                                   \
    do {                                                             \
        if constexpr (BM == 128)                                     \
            asm volatile("s_waitcnt vmcnt(4)" ::: "memory");         \
        else                                                         \
            asm volatile("s_waitcnt vmcnt(3)" ::: "memory");         \
    } while (0)

    const int NT = K >> 5;

    bf16* a0 = sA;               bf16* b0 = sB;
    bf16* a1 = sA + BM * 32;     bf16* b1 = sB + 4096;
    bf16* a2 = sA + 2 * BM * 32; bf16* b2 = sB + 2 * 4096;

    stage(a0, b0, 0);
    stage(a1, b1, NT > 1 ? 32 : 0);
    WAIT_LPS();
    __builtin_amdgcn_s_barrier();
    __builtin_amdgcn_sched_barrier(0);

    for (int kt = 0; kt < NT; ++kt) {
        bf16x8 av[AI], bv[4];
#pragma unroll
        for (int i = 0; i < AI; ++i) {
            const int r = wr + i * 16 + lrow;
            av[i] = *(const bf16x8*)&a0[r * 32 + ((lq ^ ((r >> 1) & 3)) << 3)];
        }
#pragma unroll
        for (int j = 0; j < 4; ++j) {
            const int r = wc + j * 16 + lrow;
            bv[j] = *(const bf16x8*)&b0[r * 32 + ((lq ^ ((r >> 1) & 3)) << 3)];
        }

        const int kn = (kt + 2 < NT ? kt + 2 : NT - 1) << 5;
        stage(a2, b2, kn);

#pragma unroll
        for (int i = 0; i < AI; ++i)
#pragma unroll
            for (int j = 0; j < 4; ++j)
                acc[i][j] = __builtin_amdgcn_mfma_f32_16x16x32_bf16(
                    av[i], bv[j], acc[i][j], 0, 0, 0);

        __builtin_amdgcn_sched_barrier(0);
        WAIT_LPS();
        __builtin_amdgcn_s_barrier();
        __builtin_amdgcn_sched_barrier(0);

        bf16* ta = a0; a0 = a1; a1 = a2; a2 = ta;
        bf16* tb = b0; b0 = b1; b1 = b2; b2 = tb;
    }

    asm volatile("s_waitcnt vmcnt(0)" ::: "memory");
#undef WAIT_LPS

#pragma unroll
    for (int j = 0; j < 4; ++j) {
        const int gcol = bcol + wc + j * 16 + lrow;
        const float bj = bias ? bias[gcol] : 0.0f;
#pragma unroll
        for (int i = 0; i < AI; ++i) {
            const int growb = brow + wr + i * 16 + lq * 4;
#pragma unroll
            for (int r = 0; r < 4; ++r) {
                const int grow = growb + r;
                const float val = acc[i][j][r] + bj;
                if (epi == 0) {
                    out_bf[(size_t)grow * N + gcol] = (bf16)val;
                } else {
                    out_bf[(size_t)gcol * tld + grow] = (bf16)val;
                }
            }
        }
    }
}

// fp32 gemv rows: y[n] = b[n] + W[n,:]@x, one wave per row, K=1024
__device__ __forceinline__ void gemv_rows(
    const float* __restrict__ W, const float* __restrict__ x,
    const float* __restrict__ b, float* __restrict__ y, int nbase)
{
    const int n    = nbase + (threadIdx.x >> 6);
    const int lane = threadIdx.x & 63;
    const float* row = W + (size_t)n * 1024;
    float s = 0.0f;
    for (int k = lane * 4; k < 1024; k += 256) {
        f32x4 w = *(const f32x4*)(row + k);
        f32x4 xv = *(const f32x4*)(x + k);
        s += w[0] * xv[0] + w[1] * xv[1] + w[2] * xv[2] + w[3] * xv[3];
    }
#pragma unroll
    for (int off = 32; off; off >>= 1) s += __shfl_down(s, off);
    if (lane == 0) y[n] = s + b[n];
}

// ---------------------------------------------------------------------------
// L1: segmented prep (one launch): cat | 5 casts | Wip^T,Wop^T | ones | gemv1
//   [0,16384)        cat = [prev|input] -> bf16      (8192x2048)
//   [16384,26624)    casts: wv,wih,wfg,wog,whh       (10M elems; wop dropped,
//                    replaced by the transpose below)
//   [26624,28672)    transpose-casts: Wip^T (1024 blk), Wop^T (1024 blk)
//   [28672,28680)    ones (attention weights)
//   [28680,28936)    gemv1: T1B = Wv@ip_b + bv       (f32)
// ---------------------------------------------------------------------------
__global__ void prep_k(
    const float* __restrict__ prev, const float* __restrict__ input,
    bf16* __restrict__ cat,
    const float* __restrict__ wv, const float* __restrict__ wop,
    const float* __restrict__ wih, const float* __restrict__ wfg,
    const float* __restrict__ wog, const float* __restrict__ whh,
    bf16* __restrict__ dv, bf16* __restrict__ dih,
    bf16* __restrict__ dfg, bf16* __restrict__ dog, bf16* __restrict__ dhh,
    const float* __restrict__ ipw, bf16* __restrict__ wipt,
    bf16* __restrict__ wopt,
    float* __restrict__ ones,
    const float* __restrict__ ip_b, const float* __restrict__ bv,
    float* __restrict__ t1b)
{
    __shared__ float t[32][33];
    const int b = blockIdx.x;
    if (b < 16384) {
        const int i = b * 256 + threadIdx.x;
        const int row = i >> 9;
        const int c4  = i & 511;
        f32x4 v;
        if (c4 < 256)
            v = ((const f32x4*)prev)[(size_t)row * 256 + c4];
        else
            v = ((const f32x4*)input)[(size_t)row * 256 + (c4 - 256)];
        bf16x4 o = {(bf16)v[0], (bf16)v[1], (bf16)v[2], (bf16)v[3]};
        ((bf16x4*)cat)[i] = o;
    } else if (b < 26624) {
        const int c = (b - 16384) * 256 + threadIdx.x;
        const float* s; bf16* d; int o;
        if (c < 262144)        { s = wv;  d = dv;  o = c; }
        else if (c < 1048576)  { s = wih; d = dih; o = c - 262144; }
        else if (c < 1572864)  { s = wfg; d = dfg; o = c - 1048576; }
        else if (c < 1835008)  { s = wog; d = dog; o = c - 1572864; }
        else                   { s = whh; d = dhh; o = c - 1835008; }
        f32x4 v = ((const f32x4*)s)[o];
        bf16x4 w = {(bf16)v[0], (bf16)v[1], (bf16)v[2], (bf16)v[3]};
        ((bf16x4*)d)[o] = w;
    } else if (b < 28672) {
        const int b2 = b - 26624;
        const float* src = (b2 < 1024) ? ipw : wop;
        bf16* dst = (b2 < 1024) ? wipt : wopt;
        const int b3 = b2 & 1023;
        const int bx = (b3 & 31) * 32;
        const int by = (b3 >> 5) * 32;
        const int tx = threadIdx.x & 31, ty = threadIdx.x >> 5;
#pragma unroll
        for (int i = 0; i < 32; i += 8)
            t[ty + i][tx] = src[(size_t)(by + ty + i) * 1024 + bx + tx];
        __syncthreads();
#pragma unroll
        for (int i = 0; i < 32; i += 8)
            dst[(size_t)(bx + ty + i) * 1024 + by + tx] = (bf16)t[tx][ty + i];
    } else if (b < 28680) {
        const int i = (b - 28672) * 256 + threadIdx.x;
        if (i < 2048) {
            f32x4 one = {1.0f, 1.0f, 1.0f, 1.0f};
            ((f32x4*)ones)[i] = one;
        }
    } else {
        gemv_rows(wv, ip_b, bv, t1b, (b - 28680) * 4);
    }
}

// L2: T1T=(Wv@Wip)^T (128) | P=Wih@Wop (384) | gemv2 (256) | fg (256)
__global__ __launch_bounds__(256, 2) void comb1_k(
    const bf16* __restrict__ wvb, const bf16* __restrict__ wipt,
    bf16* __restrict__ t1t,
    const bf16* __restrict__ wihb, const bf16* __restrict__ wopt,
    bf16* __restrict__ p,
    const float* __restrict__ wop_f, const float* __restrict__ t1b,
    const float* __restrict__ bop, float* __restrict__ t2b,
    const bf16* __restrict__ cat, const bf16* __restrict__ wfgb,
    const float* __restrict__ fg_b, const float* __restrict__ prev,
    bf16* __restrict__ gated)
{
    __shared__ bf16 lds[36864];
    const int b = blockIdx.x;
    if (b < 128) {
        const int by = b % 16, bx = b / 16;
        gemm_core_tb<64>(lds, lds + 3 * 64 * 32, wvb, 1024, wipt, 1024,
                         nullptr, 1024, 1024, by * 64, bx * 128, 3, t1t, 1024);
    } else if (b < 512) {
        const int id = b - 128;                 // P: [3072,1024], 48x8 tiles
        const int by = id % 48, bx = id / 48;
        gemm_core_tb<64>(lds, lds + 3 * 64 * 32, wihb, 1024, wopt, 1024,
                         nullptr, 1024, 1024, by * 64, bx * 128, 0, p, 0);
    } else if (b < 768) {
        gemv_rows(wop_f, t1b, bop, t2b, (b - 512) * 4);
    } else {
        const int id = b - 768;
        const int by = id & 31, bx = id >> 5;
        g256_core<1>(lds, cat, 2048, wfgb, 2048, 64,
                     nullptr, 0, nullptr, 0, 0,
                     fg_b, nullptr, 1024, by * 256, bx * 128,
                     gated, nullptr, prev, nullptr, nullptr, nullptr, nullptr);
    }
}

// L3: Wcomb = P @ T1T^T-form (384) | gemv3 (768)
__global__ __launch_bounds__(256, 2) void comb2_k(
    const bf16* __restrict__ p, const bf16* __restrict__ t1t,
    bf16* __restrict__ wcomb,
    const float* __restrict__ wih_f, const float* __restrict__ t2b,
    const float* __restrict__ bih, float* __restrict__ t3b)
{
    __shared__ bf16 lds[36864];
    const int b = blockIdx.x;
    if (b < 384) {
        const int by = b % 48, bx = b / 48;
        gemm_core_tb<64>(lds, lds + 3 * 64 * 32, p, 1024, t1t, 1024,
                         nullptr, 1024, 1024, by * 64, bx * 128, 0, wcomb, 0);
    } else {
        gemv_rows(wih_f, t2b, bih, t3b, (b - 384) * 4);
    }
}

// L4: g2 (Grz two-phase, 512 blk) + gi_n (256 blk)
__global__ __launch_bounds__(256, 2) void big_k(
    const bf16* __restrict__ x, const bf16* __restrict__ wcomb,
    const bf16* __restrict__ gated, const bf16* __restrict__ whh,
    const float* __restrict__ t3b, const float* __restrict__ bhh,
    bf16* __restrict__ grz,
    const bf16* __restrict__ wcomb_n, const float* __restrict__ bias_n,
    bf16* __restrict__ gni)
{
    __shared__ bf16 lds[36864];
    const int b = blockIdx.x;
    if (b < 512) {
        const int by = b & 31, bx = b >> 5;   // bx 0..15
        g256_core<0>(lds, x, 2048, wcomb, 1024, 32,
                     gated, 1024, whh, 1024, 32,
                     t3b, bhh, 2048, by * 256, bx * 128,
                     grz, nullptr, nullptr, nullptr, nullptr, nullptr, nullptr);
    } else {
        const int id = b - 512;
        const int by = id & 31, bx = id >> 5; // bx 0..7
        g256_core<0>(lds, x, 2048, wcomb_n, 1024, 32,
                     nullptr, 0, nullptr, 0, 0,
                     bias_n, nullptr, 1024, by * 256, bx * 128,
                     gni, nullptr, nullptr, nullptr, nullptr, nullptr, nullptr);
    }
}

// L5: gh_n GEMM + fused GRU combine epilogue -> UPD
__global__ __launch_bounds__(256, 2) void g3_k(
    const bf16* __restrict__ gated, const bf16* __restrict__ whh_n,
    const float* __restrict__ bhh_n,
    const bf16* __restrict__ grz, const bf16* __restrict__ gni,
    bf16* __restrict__ upd)
{
    __shared__ bf16 lds[36864];
    const int by = blockIdx.x & 31, bx = blockIdx.x >> 5;
    g256_core<4>(lds, gated, 1024, whh_n, 1024, 32,
                 nullptr, 0, nullptr, 0, 0,
                 bhh_n, nullptr, 1024, by * 256, bx * 128,
                 upd, nullptr, nullptr, nullptr, grz, gni, gated);
}

// L6: out = float(upd) * sigmoid(upd @ Wog^T + bog)
__global__ __launch_bounds__(256, 2) void og_k(
    const bf16* __restrict__ upd, const bf16* __restrict__ wog,
    const float* __restrict__ og_b, float* __restrict__ out)
{
    __shared__ bf16 lds[36864];
    const int by = blockIdx.x & 31, bx = blockIdx.x >> 5;
    g256_core<2>(lds, upd, 1024, wog, 1024, 32,
                 nullptr, 0, nullptr, 0, 0,
                 og_b, nullptr, 1024, by * 256, bx * 128,
                 nullptr, out, nullptr, upd, nullptr, nullptr, nullptr);
}

// ---------------------------------------------------------------------------
// Launch
// ---------------------------------------------------------------------------
extern "C" void kernel_launch(void* const* d_in, const int* in_sizes, int n_in,
                              void* d_out, int out_size, void* d_ws,
                              size_t ws_size, hipStream_t stream) {
    const float* input      = (const float*)d_in[0];
    const float* prev       = (const float*)d_in[1];
    const float* in_proj_w  = (const float*)d_in[2];
    const float* in_proj_b  = (const float*)d_in[3];
    const float* out_proj_w = (const float*)d_in[4];
    const float* out_proj_b = (const float*)d_in[5];
    const float* ip_w       = (const float*)d_in[6];
    const float* ip_b       = (const float*)d_in[7];
    // d_in[8]/d_in[9] (mp_w/mp_b) dead: softmax over one key == 1
    const float* fg_w  = (const float*)d_in[10];
    const float* fg_b  = (const float*)d_in[11];
    const float* og_w  = (const float*)d_in[12];
    const float* og_b  = (const float*)d_in[13];
    const float* gih_w = (const float*)d_in[14];
    const float* gih_b = (const float*)d_in[15];
    const float* ghh_w = (const float*)d_in[16];
    const float* ghh_b = (const float*)d_in[17];
    float* out = (float*)d_out;

    // ---- workspace layout (max 152 MiB, proven bound)
    char* ws = (char*)d_ws;
    const size_t MB = 1024 * 1024;
    bf16* CAT   = (bf16*)(ws);              // [0,32M)   [prev|input] bf16
    bf16* WHHB  = (bf16*)(ws + 32 * MB);    // [32,38M)  Whh bf16 (3072x1024)
    bf16* GRZ   = (bf16*)(ws + 38 * MB);    // [38,70M)  r,z sums (8192x2048)
    bf16* GNI   = (bf16*)(ws + 70 * MB);    // [70,86M)  gi_n (8192x1024)
    bf16* GATED = (bf16*)(ws + 86 * MB);    // [86,102M) gated mem
    bf16* UPD   = (bf16*)(ws + 102 * MB);   // [102,118M) updated mem
    bf16* WCOMB = (bf16*)(ws + 118 * MB);   // [118,124M) (3072x1024)
    bf16* WOGB  = (bf16*)(ws + 124 * MB);   // [124,126M)
    bf16* WFGB  = (bf16*)(ws + 126 * MB);   // [126,130M) (1024x2048)
    bf16* WVB   = (bf16*)(ws + 130 * MB);   // [130,132M)
    float* T1B  = (float*)(ws + 132 * MB);  // 4KB
    float* T2B  = (float*)(ws + 132 * MB + 8192);
    float* T3B  = (float*)(ws + 132 * MB + 16384);  // 12KB (3072 f32)
    bf16* WIHB  = (bf16*)(ws + 134 * MB);   // [134,140M) (3072x1024)
    bf16* WIPT  = (bf16*)(ws + 140 * MB);   // [140,142M)
    bf16* T1T   = (bf16*)(ws + 142 * MB);   // [142,144M)
    bf16* WOPT  = (bf16*)(ws + 144 * MB);   // [144,146M) Wop^T bf16
    bf16* P     = (bf16*)(ws + 146 * MB);   // [146,152M) Wih@Wop (3072x1024)

    const int M = B_ROWS;
    dim3 blk(256);

    // L1: prep (cat, 5 casts, Wip^T, Wop^T, ones) + gemv1
    prep_k<<<dim3(28936), blk, 0, stream>>>(
        prev, input, CAT,
        in_proj_w + 2048 * 1024, out_proj_w, gih_w, fg_w, og_w, ghh_w,
        WVB, WIHB, WFGB, WOGB, WHHB,
        ip_w, WIPT, WOPT, out + (size_t)M * 1024,
        ip_b, in_proj_b + 2048, T1B);
    // L2: T1T + P + gemv2 + fg -> GATED
    comb1_k<<<dim3(1024), blk, 0, stream>>>(
        WVB, WIPT, T1T,
        WIHB, WOPT, P,
        out_proj_w, T1B, out_proj_b, T2B,
        CAT, WFGB, fg_b, prev, GATED);
    // L3: Wcomb = P @ (Wv@Wip) + gemv3
    comb2_k<<<dim3(1152), blk, 0, stream>>>(
        P, T1T, WCOMB,
        gih_w, T2B, gih_b, T3B);
    // L4: Grz (two-phase K) + gi_n
    big_k<<<dim3(768), blk, 0, stream>>>(
        CAT + 1024, WCOMB, GATED, WHHB, T3B, ghh_b, GRZ,
        WCOMB + (size_t)2048 * 1024, T3B + 2048, GNI);
    // L5: gh_n + fused GRU combine -> UPD
    g3_k<<<dim3(256), blk, 0, stream>>>(
        GATED, WHHB + (size_t)2048 * 1024, ghh_b + 2048, GRZ, GNI, UPD);
    // L6: out = upd * sigmoid(upd @ Wog^T + bog)
    og_k<<<dim3(256), blk, 0, stream>>>(UPD, WOGB, og_b, out);
}